// Round 1
// baseline (660.550 us; speedup 1.0000x reference)
//
#include <hip/hip_runtime.h>

// ---------------- problem constants ----------------
#define LQ   20197
#define MTOT 40394           // 2 * 20197
#define DMODEL 256
#define DFFN   1024

typedef _Float16 f16;
typedef _Float16 f16x8 __attribute__((ext_vector_type(8)));
typedef _Float16 f16x4 __attribute__((ext_vector_type(4)));
typedef float    f32x4 __attribute__((ext_vector_type(4)));

// ---------------- workspace layout (bytes) ----------------
// [wT 1.51MB][B4 41.4MB][B1 20.7MB][B2 20.7MB][B3 20.7MB][B5 20.7MB][B6 41.4MB][B7 41.4MB]
// B4: off_f32 -> (later) y2_f32
// B1: src_f16 -> (later) samp_f16
// B2: query_f16 -> (later) x1_f16
// B3: value_f16 ; FFN hidden h_f16 occupies B3..B6 (exactly 82,726,912 B)
// B5: attn logits f32
// B6: src2 f32
// B7: x1 f32
#define OFF_WT 0ull
#define OFF_B4 1507328ull
#define OFF_B1 42870784ull
#define OFF_B2 63552512ull
#define OFF_B3 84234240ull
#define OFF_B5 104915968ull
#define OFF_B6 125597696ull
#define OFF_B7 166961152ull

// wT element offsets (f16 elements)
#define WT_V    0
#define WT_OFF  65536
#define WT_ATTN 131072
#define WT_OUT  163840
#define WT_W1   229376
#define WT_W2   491520
#define WT_TOTAL 753664

// ---------------- weight transpose+convert: dst[n*K+k] = (f16)src[k*N+n] ----------------
__global__ __launch_bounds__(256) void k_wconv(
    const float* __restrict__ wv, const float* __restrict__ woff,
    const float* __restrict__ wattn, const float* __restrict__ wout,
    const float* __restrict__ w1, const float* __restrict__ w2,
    f16* __restrict__ dst)
{
    int gid = blockIdx.x * 256 + threadIdx.x;
    const float* src; int Kd, Nd, base;
    if      (gid < 65536)  { src = wv;    Kd = 256;  Nd = 256;  base = 0; }
    else if (gid < 131072) { src = woff;  Kd = 256;  Nd = 256;  base = 65536; }
    else if (gid < 163840) { src = wattn; Kd = 256;  Nd = 128;  base = 131072; }
    else if (gid < 229376) { src = wout;  Kd = 256;  Nd = 256;  base = 163840; }
    else if (gid < 491520) { src = w1;    Kd = 256;  Nd = 1024; base = 229376; }
    else if (gid < 753664) { src = w2;    Kd = 1024; Nd = 256;  base = 491520; }
    else return;
    int loc = gid - base;
    int n = loc % Nd, k = loc / Nd;
    dst[base + n * Kd + k] = (f16)src[k * Nd + n];
}

// ---------------- prep: query = src + pos, cast both to f16 ----------------
__global__ __launch_bounds__(256) void k_prep(
    const float* __restrict__ src, const float* __restrict__ pos,
    f16* __restrict__ srch, f16* __restrict__ qh, int total4)
{
    int i = blockIdx.x * 256 + threadIdx.x;
    if (i >= total4) return;
    float4 s = ((const float4*)src)[i];
    float4 p = ((const float4*)pos)[i];
    f16x4 hs = { (f16)s.x, (f16)s.y, (f16)s.z, (f16)s.w };
    f16x4 hq = { (f16)(s.x + p.x), (f16)(s.y + p.y), (f16)(s.z + p.z), (f16)(s.w + p.w) };
    ((f16x4*)srch)[i] = hs;
    ((f16x4*)qh)[i]   = hq;
}

// ---------------- GEMM: C[M,N] = A[M,K](f16) * Bt[N,K](f16)^T + bias ----------------
// 64x64 tile, BK=32, 256 threads = 4 waves, each wave 16 rows x 64 cols via 4 mfma_16x16x32.
template<bool RELU, bool OUT_F16>
__global__ __launch_bounds__(256) void k_gemm(
    const f16* __restrict__ A, const f16* __restrict__ Bt,
    const float* __restrict__ bias, void* __restrict__ Cout,
    int M, int N, int K)
{
    __shared__ __align__(16) f16 As[64][48];   // stride 48 elems (96B) to spread banks
    __shared__ __align__(16) f16 Bs[64][48];
    const int t = threadIdx.x;
    const int m0 = blockIdx.x * 64, n0 = blockIdx.y * 64;
    const int wid = t >> 6, lane = t & 63;
    const int lr = t >> 2, lc = (t & 3) * 8;    // staging row / k-chunk

    const int arow = min(m0 + lr, M - 1);       // clamp: OOB rows never stored
    const f16* aptr = A + (size_t)arow * K + lc;
    const f16* bptr = Bt + (size_t)(n0 + lr) * K + lc;

    f32x4 acc[4] = {};

    for (int k0 = 0; k0 < K; k0 += 32) {
        *(int4*)&As[lr][lc] = *(const int4*)(aptr + k0);
        *(int4*)&Bs[lr][lc] = *(const int4*)(bptr + k0);
        __syncthreads();
        const int fr = lane & 15, kb = (lane >> 4) * 8;
        f16x8 af = *(const f16x8*)&As[wid * 16 + fr][kb];
#pragma unroll
        for (int nb = 0; nb < 4; ++nb) {
            f16x8 bf = *(const f16x8*)&Bs[nb * 16 + fr][kb];
            acc[nb] = __builtin_amdgcn_mfma_f32_16x16x32_f16(af, bf, acc[nb], 0, 0, 0);
        }
        __syncthreads();
    }

    const int fr = lane & 15;
    const int r4 = (lane >> 4) * 4;
#pragma unroll
    for (int nb = 0; nb < 4; ++nb) {
        const int col = n0 + nb * 16 + fr;
        const float bv = bias[col];
#pragma unroll
        for (int j = 0; j < 4; ++j) {
            const int row = m0 + wid * 16 + r4 + j;
            if (row < M) {
                float v = acc[nb][j] + bv;
                if (RELU) v = fmaxf(v, 0.f);
                if (OUT_F16) ((f16*)Cout)[(size_t)row * N + col] = (f16)v;
                else         ((float*)Cout)[(size_t)row * N + col] = v;
            }
        }
    }
}

// ---------------- fused softmax + deformable bilinear sampling ----------------
// one block (256 thr) per query token: threads = 8 heads x 32 dims
__global__ __launch_bounds__(256) void k_sample(
    const float* __restrict__ off, const float* __restrict__ attnlog,
    const f16* __restrict__ value, const float* __restrict__ ref,
    f16* __restrict__ samp)
{
    const int q = blockIdx.x, n = blockIdx.y;
    const size_t row = (size_t)n * LQ + q;
    __shared__ float s_w[8][16];
    __shared__ float s_lx[8][16];
    __shared__ float s_ly[8][16];

    const int t = threadIdx.x;
    if (t < 128) {
        const int h = t >> 4, lp = t & 15, l = lp >> 2;
        float logit = attnlog[row * 128 + h * 16 + lp];
        float mx = logit;
#pragma unroll
        for (int m = 1; m < 16; m <<= 1) mx = fmaxf(mx, __shfl_xor(mx, m));
        float e = __expf(logit - mx);
        float sum = e;
#pragma unroll
        for (int m = 1; m < 16; m <<= 1) sum += __shfl_xor(sum, m);
        s_w[h][lp] = e / sum;
        const float invW[4] = { 1.f/152.f, 1.f/76.f, 1.f/38.f, 1.f/19.f };
        const float invH[4] = { 1.f/100.f, 1.f/50.f, 1.f/25.f, 1.f/13.f };
        float ox = off[row * 256 + h * 32 + lp * 2 + 0];
        float oy = off[row * 256 + h * 32 + lp * 2 + 1];
        float rx = ref[(row * 4 + l) * 2 + 0];
        float ry = ref[(row * 4 + l) * 2 + 1];
        s_lx[h][lp] = rx + ox * invW[l];
        s_ly[h][lp] = ry + oy * invH[l];
    }
    __syncthreads();

    const int h = t >> 5, d = t & 31;
    const f16* vb = value + (size_t)n * LQ * 256 + h * 32 + d;
    const int LW[4] = { 152, 76, 38, 19 };
    const int LH[4] = { 100, 50, 25, 13 };
    const int LS[4] = { 0, 15200, 19000, 19950 };
    float acc = 0.f;
#pragma unroll
    for (int l = 0; l < 4; ++l) {
        const int W = LW[l], H = LH[l], st = LS[l];
#pragma unroll
        for (int p = 0; p < 4; ++p) {
            const int lp = l * 4 + p;
            const float w  = s_w[h][lp];
            const float x = s_lx[h][lp] * W - 0.5f;
            const float y = s_ly[h][lp] * H - 0.5f;
            const float xf = floorf(x), yf_ = floorf(y);
            const float fx = x - xf, fy = y - yf_;
            const int x0 = (int)xf, y0 = (int)yf_;
#pragma unroll
            for (int dy = 0; dy < 2; ++dy) {
#pragma unroll
                for (int dx = 0; dx < 2; ++dx) {
                    const int xi = x0 + dx, yi = y0 + dy;
                    if (xi >= 0 && xi < W && yi >= 0 && yi < H) {
                        const float cw = (dx ? fx : 1.f - fx) * (dy ? fy : 1.f - fy) * w;
                        acc += cw * (float)vb[(size_t)(st + yi * W + xi) * 256];
                    }
                }
            }
        }
    }
    samp[row * 256 + h * 32 + d] = (f16)acc;
}

// ---------------- LayerNorm: y = LN(xa + xb)*g + b ----------------
// MODE 0: write y as f32 (yf) and f16 (yh).  MODE 1: write y as f32 only.
template<int MODE>
__global__ __launch_bounds__(256) void k_ln(
    const float* __restrict__ xa, const float* __restrict__ xb,
    const float* __restrict__ g, const float* __restrict__ be,
    float* __restrict__ yf, f16* __restrict__ yh, int M)
{
    const int row = blockIdx.x * 4 + (threadIdx.x >> 6);
    const int lane = threadIdx.x & 63;
    if (row >= M) return;
    const size_t o = (size_t)row * 256 + lane * 4;
    float4 a = *(const float4*)(xa + o);
    float4 b = *(const float4*)(xb + o);
    float x0 = a.x + b.x, x1 = a.y + b.y, x2 = a.z + b.z, x3 = a.w + b.w;
    float s  = x0 + x1 + x2 + x3;
    float ss = x0*x0 + x1*x1 + x2*x2 + x3*x3;
#pragma unroll
    for (int m = 1; m < 64; m <<= 1) {
        s  += __shfl_xor(s, m);
        ss += __shfl_xor(ss, m);
    }
    const float mean = s * (1.f / 256.f);
    const float var  = ss * (1.f / 256.f) - mean * mean;
    const float rstd = rsqrtf(var + 1e-5f);
    float4 gv = *(const float4*)(g + lane * 4);
    float4 bv = *(const float4*)(be + lane * 4);
    float y0 = (x0 - mean) * rstd * gv.x + bv.x;
    float y1 = (x1 - mean) * rstd * gv.y + bv.y;
    float y2 = (x2 - mean) * rstd * gv.z + bv.z;
    float y3 = (x3 - mean) * rstd * gv.w + bv.w;
    float4 yo = { y0, y1, y2, y3 };
    *(float4*)(yf + o) = yo;
    if (MODE == 0) {
        f16x4 hv = { (f16)y0, (f16)y1, (f16)y2, (f16)y3 };
        *(f16x4*)(yh + o) = hv;
    }
}

// ---------------- launch ----------------
extern "C" void kernel_launch(void* const* d_in, const int* in_sizes, int n_in,
                              void* d_out, int out_size, void* d_ws, size_t ws_size,
                              hipStream_t stream) {
    const float* src   = (const float*)d_in[0];
    const float* pos   = (const float*)d_in[1];
    const float* ref   = (const float*)d_in[2];
    const float* w_value = (const float*)d_in[5];
    const float* b_value = (const float*)d_in[6];
    const float* w_off   = (const float*)d_in[7];
    const float* b_off   = (const float*)d_in[8];
    const float* w_attn  = (const float*)d_in[9];
    const float* b_attn  = (const float*)d_in[10];
    const float* w_out   = (const float*)d_in[11];
    const float* b_out   = (const float*)d_in[12];
    const float* g1    = (const float*)d_in[13];
    const float* beta1 = (const float*)d_in[14];
    const float* w1    = (const float*)d_in[15];
    const float* b1    = (const float*)d_in[16];
    const float* w2    = (const float*)d_in[17];
    const float* b2    = (const float*)d_in[18];
    const float* g2    = (const float*)d_in[19];
    const float* beta2 = (const float*)d_in[20];

    char* ws = (char*)d_ws;
    f16*   wT      = (f16*)(ws + OFF_WT);
    float* offb    = (float*)(ws + OFF_B4);   // off logits f32 [M,256]
    float* y2buf   = (float*)(ws + OFF_B4);   // later: FFN2 out f32 [M,256]
    f16*   srch    = (f16*)(ws + OFF_B1);     // src f16 [M,256]
    f16*   samph   = (f16*)(ws + OFF_B1);     // later: sampled out f16 [M,256]
    f16*   qh      = (f16*)(ws + OFF_B2);     // query f16 [M,256]
    f16*   x1h     = (f16*)(ws + OFF_B2);     // later: LN1 out f16 [M,256]
    f16*   valueh  = (f16*)(ws + OFF_B3);     // value f16 [M,256]
    f16*   hh      = (f16*)(ws + OFF_B3);     // later: FFN hidden f16 [M,1024] (B3..B6)
    float* attnlg  = (float*)(ws + OFF_B5);   // attn logits f32 [M,128]
    float* src2    = (float*)(ws + OFF_B6);   // attn output f32 [M,256]
    float* x1f     = (float*)(ws + OFF_B7);   // LN1 out f32 [M,256]
    float* outp    = (float*)d_out;

    const int M = MTOT;

    // 1. weights -> f16 transposed [N][K]
    k_wconv<<<(WT_TOTAL + 255) / 256, 256, 0, stream>>>(w_value, w_off, w_attn, w_out, w1, w2, wT);
    // 2. prep
    k_prep<<<(M * 64 + 255) / 256, 256, 0, stream>>>(src, pos, srch, qh, M * 64);

    const int MB = (M + 63) / 64;
    // 3. value = src @ w_value + b_value  (f16 out)
    k_gemm<false, true><<<dim3(MB, 4), 256, 0, stream>>>(srch, wT + WT_V, b_value, valueh, M, 256, 256);
    // 4. off logits (f32), attn logits (f32)
    k_gemm<false, false><<<dim3(MB, 4), 256, 0, stream>>>(qh, wT + WT_OFF, b_off, offb, M, 256, 256);
    k_gemm<false, false><<<dim3(MB, 2), 256, 0, stream>>>(qh, wT + WT_ATTN, b_attn, attnlg, M, 128, 256);
    // 5. softmax + bilinear sampling
    k_sample<<<dim3(LQ, 2), 256, 0, stream>>>(offb, attnlg, valueh, ref, samph);
    // 6. out projection -> src2 f32
    k_gemm<false, false><<<dim3(MB, 4), 256, 0, stream>>>(samph, wT + WT_OUT, b_out, src2, M, 256, 256);
    // 7. LN1: x1 = LN(src + src2)
    k_ln<0><<<(M + 3) / 4, 256, 0, stream>>>(src, src2, g1, beta1, x1f, x1h, M);
    // 8. FFN1: h = relu(x1 @ w1 + b1) f16
    k_gemm<true, true><<<dim3(MB, 16), 256, 0, stream>>>(x1h, wT + WT_W1, b1, hh, M, 1024, 256);
    // 9. FFN2: y2 = h @ w2 + b2 f32
    k_gemm<false, false><<<dim3(MB, 4), 256, 0, stream>>>(hh, wT + WT_W2, b2, y2buf, M, 256, 1024);
    // 10. LN2 -> d_out
    k_ln<1><<<(M + 3) / 4, 256, 0, stream>>>(x1f, y2buf, g2, beta2, outp, nullptr, M);

    (void)in_sizes; (void)n_in; (void)out_size; (void)ws_size;
}

// Round 2
// 365.344 us; speedup vs baseline: 1.8080x; 1.8080x over previous
//
#include <hip/hip_runtime.h>

// ---------------- problem constants ----------------
#define LQ   20197
#define MTOT 40394           // 2 * 20197

typedef _Float16 f16;
typedef _Float16 f16x8 __attribute__((ext_vector_type(8)));
typedef _Float16 f16x4 __attribute__((ext_vector_type(4)));
typedef _Float16 f16x2 __attribute__((ext_vector_type(2)));
typedef float    f32x4 __attribute__((ext_vector_type(4)));

// ---------------- workspace layout (bytes) ----------------
#define OFF_WT 0ull
#define OFF_B4 1507328ull      // off f32 [M,256] -> later FFN2 out f32
#define OFF_B1 42870784ull     // src f16 -> later samp f16
#define OFF_B2 63552512ull     // query f16 -> later x1 f16
#define OFF_B3 84234240ull     // valueT f16 [8][M][32]; later FFN hidden (B3..B6)
#define OFF_B5 104915968ull    // attn logits f32 [M,128]
#define OFF_B6 125597696ull    // src2 f32 [M,256]
#define OFF_B7 166961152ull    // x1 f32 [M,256]

// wT element offsets (f16 elements)
#define WT_V    0
#define WT_OFF  65536
#define WT_ATTN 131072
#define WT_OUT  163840
#define WT_W1   229376
#define WT_W2   491520
#define WT_TOTAL 753664

// ---------------- async global->LDS, 16B per lane ----------------
__device__ __forceinline__ void gload_lds16(const f16* g, f16* l) {
    __builtin_amdgcn_global_load_lds(
        (const __attribute__((address_space(1))) unsigned int*)g,
        (__attribute__((address_space(3))) unsigned int*)l,
        16, 0, 0);
}

// ---------------- weight transpose+convert: dst[n*K+k] = (f16)src[k*N+n] ----------------
__global__ __launch_bounds__(256) void k_wconv(
    const float* __restrict__ wv, const float* __restrict__ woff,
    const float* __restrict__ wattn, const float* __restrict__ wout,
    const float* __restrict__ w1, const float* __restrict__ w2,
    f16* __restrict__ dst)
{
    int gid = blockIdx.x * 256 + threadIdx.x;
    const float* src; int Kd, Nd, base;
    if      (gid < 65536)  { src = wv;    Kd = 256;  Nd = 256;  base = 0; }
    else if (gid < 131072) { src = woff;  Kd = 256;  Nd = 256;  base = 65536; }
    else if (gid < 163840) { src = wattn; Kd = 256;  Nd = 128;  base = 131072; }
    else if (gid < 229376) { src = wout;  Kd = 256;  Nd = 256;  base = 163840; }
    else if (gid < 491520) { src = w1;    Kd = 256;  Nd = 1024; base = 229376; }
    else if (gid < 753664) { src = w2;    Kd = 1024; Nd = 256;  base = 491520; }
    else return;
    int loc = gid - base;
    int n = loc % Nd, k = loc / Nd;
    dst[base + n * Kd + k] = (f16)src[k * Nd + n];
}

// ---------------- prep: query = src + pos, cast both to f16 ----------------
__global__ __launch_bounds__(256) void k_prep(
    const float* __restrict__ src, const float* __restrict__ pos,
    f16* __restrict__ srch, f16* __restrict__ qh, int total4)
{
    int i = blockIdx.x * 256 + threadIdx.x;
    if (i >= total4) return;
    float4 s = ((const float4*)src)[i];
    float4 p = ((const float4*)pos)[i];
    f16x4 hs = { (f16)s.x, (f16)s.y, (f16)s.z, (f16)s.w };
    f16x4 hq = { (f16)(s.x + p.x), (f16)(s.y + p.y), (f16)(s.z + p.z), (f16)(s.w + p.w) };
    ((f16x4*)srch)[i] = hs;
    ((f16x4*)qh)[i]   = hq;
}

// ---------------- GEMM 128x128 tile, BK=32, global_load_lds staging ----------------
// C[M,N] = A[M,K](f16) * Bt[N,K](f16)^T + bias
// OUTM: 0 = f32 row-major, 1 = f16 row-major, 2 = f16 head-blocked [N/32][M][32]
template<bool RELU, int OUTM>
__global__ __launch_bounds__(256) void k_gemm128(
    const f16* __restrict__ A, const f16* __restrict__ Bt,
    const float* __restrict__ bias, void* __restrict__ Cout,
    int M, int N, int K)
{
    __shared__ __align__(16) f16 As[128 * 32];
    __shared__ __align__(16) f16 Bs[128 * 32];
    const int t = threadIdx.x, wid = t >> 6, lane = t & 63;
    const int m0 = blockIdx.x * 128, n0 = blockIdx.y * 128;

    // staging: 8 chunks of 1KB per matrix; wave w does chunks w and w+4.
    // chunk c, lane l -> row c*16 + (l>>2), k-chunk (l&3)*8
    const int c0 = wid, c1 = wid + 4;
    const int sr = lane >> 2, sk = (lane & 3) * 8;
    const int ra0 = min(m0 + c0 * 16 + sr, M - 1);
    const int ra1 = min(m0 + c1 * 16 + sr, M - 1);
    const f16* pa0 = A + (size_t)ra0 * K + sk;
    const f16* pa1 = A + (size_t)ra1 * K + sk;
    const f16* pb0 = Bt + (size_t)(n0 + c0 * 16 + sr) * K + sk;
    const f16* pb1 = Bt + (size_t)(n0 + c1 * 16 + sr) * K + sk;
    f16* lA0 = As + c0 * 512; f16* lA1 = As + c1 * 512;
    f16* lB0 = Bs + c0 * 512; f16* lB1 = Bs + c1 * 512;

    const int wr = wid >> 1, wc = wid & 1;
    const int fr = lane & 15, kb = (lane >> 4) * 8;

    f32x4 acc[4][4] = {};

    for (int k0 = 0; k0 < K; k0 += 32) {
        gload_lds16(pa0 + k0, lA0);
        gload_lds16(pa1 + k0, lA1);
        gload_lds16(pb0 + k0, lB0);
        gload_lds16(pb1 + k0, lB1);
        __syncthreads();   // compiler emits vmcnt(0) drain before barrier
        f16x8 af[4], bf[4];
#pragma unroll
        for (int i = 0; i < 4; ++i)
            af[i] = *(const f16x8*)&As[(wr * 64 + i * 16 + fr) * 32 + kb];
#pragma unroll
        for (int i = 0; i < 4; ++i)
            bf[i] = *(const f16x8*)&Bs[(wc * 64 + i * 16 + fr) * 32 + kb];
#pragma unroll
        for (int mi = 0; mi < 4; ++mi)
#pragma unroll
            for (int ni = 0; ni < 4; ++ni)
                acc[mi][ni] = __builtin_amdgcn_mfma_f32_16x16x32_f16(af[mi], bf[ni], acc[mi][ni], 0, 0, 0);
        __syncthreads();
    }

    const int r4 = (lane >> 4) * 4;
#pragma unroll
    for (int ni = 0; ni < 4; ++ni) {
        const int col = n0 + wc * 64 + ni * 16 + fr;
        const float bv = bias[col];
#pragma unroll
        for (int mi = 0; mi < 4; ++mi) {
            const int rbase = m0 + wr * 64 + mi * 16 + r4;
#pragma unroll
            for (int j = 0; j < 4; ++j) {
                const int row = rbase + j;
                if (row < M) {
                    float v = acc[mi][ni][j] + bv;
                    if (RELU) v = fmaxf(v, 0.f);
                    if (OUTM == 0)      ((float*)Cout)[(size_t)row * N + col] = v;
                    else if (OUTM == 1) ((f16*)Cout)[(size_t)row * N + col] = (f16)v;
                    else ((f16*)Cout)[((size_t)(col >> 5) * M + row) * 32 + (col & 31)] = (f16)v;
                }
            }
        }
    }
}

// ---------------- fused softmax + deformable bilinear sampling ----------------
// block = 2 tokens; threads = 2 sub x 8 heads x 16 lanes.
// Phase 1: one thread per (sub,h,level,point) -> softmax, clamped base idx, masked weights.
// Phase 2: lane owns f16x2 dim-pair; 4 gathers + 8 FMA per point.
__global__ __launch_bounds__(256) void k_sample(
    const float* __restrict__ off, const float* __restrict__ attnlog,
    const f16* __restrict__ valueT, const float* __restrict__ ref,
    f16* __restrict__ samp)
{
    __shared__ int4   s_g[2][8][16];
    __shared__ float4 s_w[2][8][16];
    const int t = threadIdx.x;
    const int sub = t >> 7;
    const int tok = blockIdx.x * 2 + sub;
    {
        const int h = (t >> 4) & 7, lp = t & 15, l = lp >> 2;
        float logit = attnlog[(size_t)tok * 128 + h * 16 + lp];
        float mx = logit;
#pragma unroll
        for (int m = 1; m < 16; m <<= 1) mx = fmaxf(mx, __shfl_xor(mx, m));
        float e = __expf(logit - mx);
        float sum = e;
#pragma unroll
        for (int m = 1; m < 16; m <<= 1) sum += __shfl_xor(sum, m);
        const float aw = e / sum;

        const float fW = (l == 0) ? 152.f : (l == 1) ? 76.f : (l == 2) ? 38.f : 19.f;
        const float fH = (l == 0) ? 100.f : (l == 1) ? 50.f : (l == 2) ? 25.f : 13.f;
        const int   W  = (l == 0) ? 152 : (l == 1) ? 76 : (l == 2) ? 38 : 19;
        const int   H  = (l == 0) ? 100 : (l == 1) ? 50 : (l == 2) ? 25 : 13;
        const int   st = (l == 0) ? 0 : (l == 1) ? 15200 : (l == 2) ? 19000 : 19950;

        const float ox = off[(size_t)tok * 256 + h * 32 + lp * 2 + 0];
        const float oy = off[(size_t)tok * 256 + h * 32 + lp * 2 + 1];
        const float rx = ref[(size_t)tok * 8 + l * 2 + 0];
        const float ry = ref[(size_t)tok * 8 + l * 2 + 1];
        const float x = rx * fW + ox - 0.5f;
        const float y = ry * fH + oy - 0.5f;
        const float xf = floorf(x), yf = floorf(y);
        const float fx = x - xf, fy = y - yf;
        const int x0 = (int)xf, y0 = (int)yf;

        const bool vx0 = (x0 >= 0) && (x0 < W);
        const bool vx1 = (x0 >= -1) && (x0 < W - 1);
        const bool vy0 = (y0 >= 0) && (y0 < H);
        const bool vy1 = (y0 >= -1) && (y0 < H - 1);
        const int x0c = min(max(x0, 0), W - 1), x1c = min(max(x0 + 1, 0), W - 1);
        const int y0c = min(max(y0, 0), H - 1), y1c = min(max(y0 + 1, 0), H - 1);

        const int n = (tok >= LQ) ? 1 : 0;
        const int base = n * LQ + st + y0c * W + x0c;
        const int dxs = x1c - x0c, dys = (y1c - y0c) * W;
        s_g[sub][h][lp] = make_int4(base, dxs, dys, dys + dxs);

        const float w00 = (vx0 && vy0) ? (1.f - fx) * (1.f - fy) * aw : 0.f;
        const float w01 = (vx1 && vy0) ? fx * (1.f - fy) * aw : 0.f;
        const float w10 = (vx0 && vy1) ? (1.f - fx) * fy * aw : 0.f;
        const float w11 = (vx1 && vy1) ? fx * fy * aw : 0.f;
        s_w[sub][h][lp] = make_float4(w00, w01, w10, w11);
    }
    __syncthreads();

    const int h = (t >> 4) & 7, ln = t & 15;
    // valueT: [8][M][32] f16 -> f16x2 view [8][M][16]
    const f16x2* vp = (const f16x2*)valueT + (size_t)h * (MTOT * 16) + ln;
    float ax = 0.f, ay = 0.f;
#pragma unroll 4
    for (int p = 0; p < 16; ++p) {
        const int4   g = s_g[sub][h][p];
        const float4 w = s_w[sub][h][p];
        const f16x2* pb = vp + (size_t)g.x * 16;
        const f16x2 v00 = pb[0];
        const f16x2 v01 = pb[(size_t)g.y * 16];
        const f16x2 v10 = pb[(size_t)g.z * 16];
        const f16x2 v11 = pb[(size_t)g.w * 16];
        ax += w.x * (float)v00.x + w.y * (float)v01.x + w.z * (float)v10.x + w.w * (float)v11.x;
        ay += w.x * (float)v00.y + w.y * (float)v01.y + w.z * (float)v10.y + w.w * (float)v11.y;
    }
    f16x2 o = { (f16)ax, (f16)ay };
    *(f16x2*)&samp[(size_t)tok * 256 + h * 32 + ln * 2] = o;
}

// ---------------- LayerNorm: y = LN(xa + xb)*g + b ----------------
template<int MODE>
__global__ __launch_bounds__(256) void k_ln(
    const float* __restrict__ xa, const float* __restrict__ xb,
    const float* __restrict__ g, const float* __restrict__ be,
    float* __restrict__ yf, f16* __restrict__ yh, int M)
{
    const int row = blockIdx.x * 4 + (threadIdx.x >> 6);
    const int lane = threadIdx.x & 63;
    if (row >= M) return;
    const size_t o = (size_t)row * 256 + lane * 4;
    float4 a = *(const float4*)(xa + o);
    float4 b = *(const float4*)(xb + o);
    float x0 = a.x + b.x, x1 = a.y + b.y, x2 = a.z + b.z, x3 = a.w + b.w;
    float s  = x0 + x1 + x2 + x3;
    float ss = x0*x0 + x1*x1 + x2*x2 + x3*x3;
#pragma unroll
    for (int m = 1; m < 64; m <<= 1) {
        s  += __shfl_xor(s, m);
        ss += __shfl_xor(ss, m);
    }
    const float mean = s * (1.f / 256.f);
    const float var  = ss * (1.f / 256.f) - mean * mean;
    const float rstd = rsqrtf(var + 1e-5f);
    float4 gv = *(const float4*)(g + lane * 4);
    float4 bv = *(const float4*)(be + lane * 4);
    float y0 = (x0 - mean) * rstd * gv.x + bv.x;
    float y1 = (x1 - mean) * rstd * gv.y + bv.y;
    float y2 = (x2 - mean) * rstd * gv.z + bv.z;
    float y3 = (x3 - mean) * rstd * gv.w + bv.w;
    float4 yo = { y0, y1, y2, y3 };
    *(float4*)(yf + o) = yo;
    if (MODE == 0) {
        f16x4 hv = { (f16)y0, (f16)y1, (f16)y2, (f16)y3 };
        *(f16x4*)(yh + o) = hv;
    }
}

// ---------------- launch ----------------
extern "C" void kernel_launch(void* const* d_in, const int* in_sizes, int n_in,
                              void* d_out, int out_size, void* d_ws, size_t ws_size,
                              hipStream_t stream) {
    const float* src   = (const float*)d_in[0];
    const float* pos   = (const float*)d_in[1];
    const float* ref   = (const float*)d_in[2];
    const float* w_value = (const float*)d_in[5];
    const float* b_value = (const float*)d_in[6];
    const float* w_off   = (const float*)d_in[7];
    const float* b_off   = (const float*)d_in[8];
    const float* w_attn  = (const float*)d_in[9];
    const float* b_attn  = (const float*)d_in[10];
    const float* w_out   = (const float*)d_in[11];
    const float* b_out   = (const float*)d_in[12];
    const float* g1    = (const float*)d_in[13];
    const float* beta1 = (const float*)d_in[14];
    const float* w1    = (const float*)d_in[15];
    const float* b1    = (const float*)d_in[16];
    const float* w2    = (const float*)d_in[17];
    const float* b2    = (const float*)d_in[18];
    const float* g2    = (const float*)d_in[19];
    const float* beta2 = (const float*)d_in[20];

    char* ws = (char*)d_ws;
    f16*   wT      = (f16*)(ws + OFF_WT);
    float* offb    = (float*)(ws + OFF_B4);   // off f32 [M,256]
    float* y2buf   = (float*)(ws + OFF_B4);   // later: FFN2 out f32
    f16*   srch    = (f16*)(ws + OFF_B1);     // src f16
    f16*   samph   = (f16*)(ws + OFF_B1);     // later: sampled out f16
    f16*   qh      = (f16*)(ws + OFF_B2);     // query f16
    f16*   x1h     = (f16*)(ws + OFF_B2);     // later: LN1 out f16
    f16*   valueT  = (f16*)(ws + OFF_B3);     // value f16 head-blocked [8][M][32]
    f16*   hh      = (f16*)(ws + OFF_B3);     // later: FFN hidden f16 [M,1024]
    float* attnlg  = (float*)(ws + OFF_B5);   // attn logits f32 [M,128]
    float* src2    = (float*)(ws + OFF_B6);   // attn output f32
    float* x1f     = (float*)(ws + OFF_B7);   // LN1 out f32
    float* outp    = (float*)d_out;

    const int M = MTOT;
    const int MB = (M + 127) / 128;

    k_wconv<<<(WT_TOTAL + 255) / 256, 256, 0, stream>>>(w_value, w_off, w_attn, w_out, w1, w2, wT);
    k_prep<<<(M * 64 + 255) / 256, 256, 0, stream>>>(src, pos, srch, qh, M * 64);

    // value = src @ w_value + b_value -> head-blocked f16
    k_gemm128<false, 2><<<dim3(MB, 2), 256, 0, stream>>>(srch, wT + WT_V, b_value, valueT, M, 256, 256);
    // off logits f32, attn logits f32
    k_gemm128<false, 0><<<dim3(MB, 2), 256, 0, stream>>>(qh, wT + WT_OFF, b_off, offb, M, 256, 256);
    k_gemm128<false, 0><<<dim3(MB, 1), 256, 0, stream>>>(qh, wT + WT_ATTN, b_attn, attnlg, M, 128, 256);
    // softmax + bilinear sampling (2 tokens per block)
    k_sample<<<dim3(MTOT / 2), 256, 0, stream>>>(offb, attnlg, valueT, ref, samph);
    // out projection -> src2 f32
    k_gemm128<false, 0><<<dim3(MB, 2), 256, 0, stream>>>(samph, wT + WT_OUT, b_out, src2, M, 256, 256);
    // LN1
    k_ln<0><<<(M + 3) / 4, 256, 0, stream>>>(src, src2, g1, beta1, x1f, x1h, M);
    // FFN1: h = relu(x1 @ w1 + b1) f16
    k_gemm128<true, 1><<<dim3(MB, 8), 256, 0, stream>>>(x1h, wT + WT_W1, b1, hh, M, 1024, 256);
    // FFN2: y2 = h @ w2 + b2 f32
    k_gemm128<false, 0><<<dim3(MB, 2), 256, 0, stream>>>(hh, wT + WT_W2, b2, y2buf, M, 256, 1024);
    // LN2 -> d_out
    k_ln<1><<<(M + 3) / 4, 256, 0, stream>>>(x1f, y2buf, g2, beta2, outp, nullptr, M);

    (void)in_sizes; (void)n_in; (void)out_size; (void)ws_size;
}

// Round 3
// 333.019 us; speedup vs baseline: 1.9835x; 1.0971x over previous
//
#include <hip/hip_runtime.h>

// ---------------- problem constants ----------------
#define LQ   20197
#define MTOT 40394           // 2 * 20197

typedef _Float16 f16;
typedef _Float16 f16x8 __attribute__((ext_vector_type(8)));
typedef _Float16 f16x4 __attribute__((ext_vector_type(4)));
typedef _Float16 f16x2 __attribute__((ext_vector_type(2)));
typedef float    f32x4 __attribute__((ext_vector_type(4)));

// ---------------- workspace layout (bytes) ----------------
#define OFF_WT 0ull
#define OFF_B4 1507328ull      // oa f16 [M,384] (31MB) -> later FFN2 out f32 [M,256]
#define OFF_B1 42870784ull     // src f16 -> later samp f16
#define OFF_B2 63552512ull     // query f16 -> later x1 f16
#define OFF_B3 84234240ull     // valueT f16 [8][M][32]; later FFN hidden (B3..B6)
#define OFF_B5 104915968ull    // bias_oa f32 [384]
#define OFF_B6 125597696ull    // src2 f32 [M,256]
#define OFF_B7 166961152ull    // x1 f32 [M,256]

// wT element offsets (f16 elements)
#define WT_V    0
#define WT_OFF  65536          // off rows [256][256] then attn rows [128][256] contiguous
#define WT_ATTN 131072
#define WT_OUT  163840
#define WT_W1   229376
#define WT_W2   491520
#define WT_TOTAL 753664
#define WCONV_TOTAL (WT_TOTAL + 384)

// ---------------- async global->LDS, 16B per lane ----------------
__device__ __forceinline__ void gload_lds16(const f16* g, f16* l) {
    __builtin_amdgcn_global_load_lds(
        (const __attribute__((address_space(1))) unsigned int*)g,
        (__attribute__((address_space(3))) unsigned int*)l,
        16, 0, 0);
}

// ---------------- weight transpose+convert + bias concat ----------------
__global__ __launch_bounds__(256) void k_wconv(
    const float* __restrict__ wv, const float* __restrict__ woff,
    const float* __restrict__ wattn, const float* __restrict__ wout,
    const float* __restrict__ w1, const float* __restrict__ w2,
    const float* __restrict__ boff, const float* __restrict__ battn,
    f16* __restrict__ dst, float* __restrict__ biasoa)
{
    int gid = blockIdx.x * 256 + threadIdx.x;
    if (gid >= WCONV_TOTAL) return;
    if (gid >= WT_TOTAL) {
        int i = gid - WT_TOTAL;
        biasoa[i] = (i < 256) ? boff[i] : battn[i - 256];
        return;
    }
    const float* src; int Kd, Nd, base;
    if      (gid < 65536)  { src = wv;    Kd = 256;  Nd = 256;  base = 0; }
    else if (gid < 131072) { src = woff;  Kd = 256;  Nd = 256;  base = 65536; }
    else if (gid < 163840) { src = wattn; Kd = 256;  Nd = 128;  base = 131072; }
    else if (gid < 229376) { src = wout;  Kd = 256;  Nd = 256;  base = 163840; }
    else if (gid < 491520) { src = w1;    Kd = 256;  Nd = 1024; base = 229376; }
    else                   { src = w2;    Kd = 1024; Nd = 256;  base = 491520; }
    int loc = gid - base;
    int n = loc % Nd, k = loc / Nd;
    dst[base + n * Kd + k] = (f16)src[k * Nd + n];
}

// ---------------- prep: query = src + pos, cast both to f16 ----------------
__global__ __launch_bounds__(256) void k_prep(
    const float* __restrict__ src, const float* __restrict__ pos,
    f16* __restrict__ srch, f16* __restrict__ qh, int total4)
{
    int i = blockIdx.x * 256 + threadIdx.x;
    if (i >= total4) return;
    float4 s = ((const float4*)src)[i];
    float4 p = ((const float4*)pos)[i];
    f16x4 hs = { (f16)s.x, (f16)s.y, (f16)s.z, (f16)s.w };
    f16x4 hq = { (f16)(s.x + p.x), (f16)(s.y + p.y), (f16)(s.z + p.z), (f16)(s.w + p.w) };
    ((f16x4*)srch)[i] = hs;
    ((f16x4*)qh)[i]   = hq;
}

// ---------------- GEMM 128x128 tile, BK=32, global_load_lds staging ----------------
// C[M,N] = A[M,K](f16) * Bt[N,K](f16)^T + bias
// OUTM: 0 = f32 row-major, 1 = f16 row-major, 2 = f16 head-blocked [N/32][M][32]
template<bool RELU, int OUTM>
__global__ __launch_bounds__(256) void k_gemm128(
    const f16* __restrict__ A, const f16* __restrict__ Bt,
    const float* __restrict__ bias, void* __restrict__ Cout,
    int M, int N, int K)
{
    __shared__ __align__(16) f16 As[128 * 32];
    __shared__ __align__(16) f16 Bs[128 * 32];
    const int t = threadIdx.x, wid = t >> 6, lane = t & 63;
    const int m0 = blockIdx.x * 128, n0 = blockIdx.y * 128;

    const int c0 = wid, c1 = wid + 4;
    const int sr = lane >> 2, sk = (lane & 3) * 8;
    const int ra0 = min(m0 + c0 * 16 + sr, M - 1);
    const int ra1 = min(m0 + c1 * 16 + sr, M - 1);
    const f16* pa0 = A + (size_t)ra0 * K + sk;
    const f16* pa1 = A + (size_t)ra1 * K + sk;
    const f16* pb0 = Bt + (size_t)(n0 + c0 * 16 + sr) * K + sk;
    const f16* pb1 = Bt + (size_t)(n0 + c1 * 16 + sr) * K + sk;
    f16* lA0 = As + c0 * 512; f16* lA1 = As + c1 * 512;
    f16* lB0 = Bs + c0 * 512; f16* lB1 = Bs + c1 * 512;

    const int wr = wid >> 1, wc = wid & 1;
    const int fr = lane & 15, kb = (lane >> 4) * 8;

    f32x4 acc[4][4] = {};

    for (int k0 = 0; k0 < K; k0 += 32) {
        gload_lds16(pa0 + k0, lA0);
        gload_lds16(pa1 + k0, lA1);
        gload_lds16(pb0 + k0, lB0);
        gload_lds16(pb1 + k0, lB1);
        __syncthreads();
        f16x8 af[4], bf[4];
#pragma unroll
        for (int i = 0; i < 4; ++i)
            af[i] = *(const f16x8*)&As[(wr * 64 + i * 16 + fr) * 32 + kb];
#pragma unroll
        for (int i = 0; i < 4; ++i)
            bf[i] = *(const f16x8*)&Bs[(wc * 64 + i * 16 + fr) * 32 + kb];
#pragma unroll
        for (int mi = 0; mi < 4; ++mi)
#pragma unroll
            for (int ni = 0; ni < 4; ++ni)
                acc[mi][ni] = __builtin_amdgcn_mfma_f32_16x16x32_f16(af[mi], bf[ni], acc[mi][ni], 0, 0, 0);
        __syncthreads();
    }

    const int r4 = (lane >> 4) * 4;
#pragma unroll
    for (int ni = 0; ni < 4; ++ni) {
        const int col = n0 + wc * 64 + ni * 16 + fr;
        if (col >= N) continue;
        const float bv = bias[col];
#pragma unroll
        for (int mi = 0; mi < 4; ++mi) {
            const int rbase = m0 + wr * 64 + mi * 16 + r4;
#pragma unroll
            for (int j = 0; j < 4; ++j) {
                const int row = rbase + j;
                if (row < M) {
                    float v = acc[mi][ni][j] + bv;
                    if (RELU) v = fmaxf(v, 0.f);
                    if (OUTM == 0)      ((float*)Cout)[(size_t)row * N + col] = v;
                    else if (OUTM == 1) ((f16*)Cout)[(size_t)row * N + col] = (f16)v;
                    else ((f16*)Cout)[((size_t)(col >> 5) * M + row) * 32 + (col & 31)] = (f16)v;
                }
            }
        }
    }
}

// ---------------- fused softmax + deformable bilinear sampling ----------------
// block = 2 tokens; threads = 2 sub x 8 heads x 16 lanes.
// oa: f16 [M,384] = offsets (0..255) | attn logits (256..383)
// Phase 1: one thread per (sub,h,level,point): softmax, 4 absolute gather indices,
//          4 validity-masked pre-multiplied f16 weights.
// Phase 2: lane owns f16x2 dim-pair; per point 4 dword gathers + 4 pack + 4 v_dot2_f32_f16.
__global__ __launch_bounds__(256) void k_sample(
    const f16* __restrict__ oa, const f16* __restrict__ valueT,
    const float* __restrict__ ref, f16* __restrict__ samp)
{
    __shared__ int4  s_g[2][8][17];   // pad 17: avoid 4-way bank conflict across head groups
    __shared__ f16x4 s_w[2][8][17];
    const int t = threadIdx.x;
    const int sub = t >> 7;
    const int tok = blockIdx.x * 2 + sub;
    {
        const int h = (t >> 4) & 7, lp = t & 15, l = lp >> 2;
        const size_t row = (size_t)tok * 384;
        float logit = (float)oa[row + 256 + h * 16 + lp];
        float mx = logit;
#pragma unroll
        for (int m = 1; m < 16; m <<= 1) mx = fmaxf(mx, __shfl_xor(mx, m));
        float e = __expf(logit - mx);
        float sum = e;
#pragma unroll
        for (int m = 1; m < 16; m <<= 1) sum += __shfl_xor(sum, m);
        const float aw = e / sum;

        const float fW = (l == 0) ? 152.f : (l == 1) ? 76.f : (l == 2) ? 38.f : 19.f;
        const float fH = (l == 0) ? 100.f : (l == 1) ? 50.f : (l == 2) ? 25.f : 13.f;
        const int   W  = (l == 0) ? 152 : (l == 1) ? 76 : (l == 2) ? 38 : 19;
        const int   H  = (l == 0) ? 100 : (l == 1) ? 50 : (l == 2) ? 25 : 13;
        const int   st = (l == 0) ? 0 : (l == 1) ? 15200 : (l == 2) ? 19000 : 19950;

        const f16x2 ov = *(const f16x2*)&oa[row + h * 32 + lp * 2];
        const float rx = ref[(size_t)tok * 8 + l * 2 + 0];
        const float ry = ref[(size_t)tok * 8 + l * 2 + 1];
        const float x = rx * fW + (float)ov.x - 0.5f;
        const float y = ry * fH + (float)ov.y - 0.5f;
        const float xf = floorf(x), yf = floorf(y);
        const float fx = x - xf, fy = y - yf;
        const int x0 = (int)xf, y0 = (int)yf;

        const bool vx0 = (x0 >= 0) && (x0 < W);
        const bool vx1 = (x0 >= -1) && (x0 < W - 1);
        const bool vy0 = (y0 >= 0) && (y0 < H);
        const bool vy1 = (y0 >= -1) && (y0 < H - 1);
        const int x0c = min(max(x0, 0), W - 1), x1c = min(max(x0 + 1, 0), W - 1);
        const int y0c = min(max(y0, 0), H - 1), y1c = min(max(y0 + 1, 0), H - 1);

        const int n = (tok >= LQ) ? 1 : 0;
        const int i00 = n * LQ + st + y0c * W + x0c;
        const int dxs = x1c - x0c, dys = (y1c - y0c) * W;
        s_g[sub][h][lp] = make_int4(i00, i00 + dxs, i00 + dys, i00 + dys + dxs);

        const float w00 = (vx0 && vy0) ? (1.f - fx) * (1.f - fy) * aw : 0.f;
        const float w01 = (vx1 && vy0) ? fx * (1.f - fy) * aw : 0.f;
        const float w10 = (vx0 && vy1) ? (1.f - fx) * fy * aw : 0.f;
        const float w11 = (vx1 && vy1) ? fx * fy * aw : 0.f;
        f16x4 wv = { (f16)w00, (f16)w01, (f16)w10, (f16)w11 };
        s_w[sub][h][lp] = wv;
    }
    __syncthreads();

    const int h = (t >> 4) & 7, ln = t & 15;
    // valueT: [8][M][32] f16; per-thread u32 byte base for (h, ln) dim-pair
    const unsigned int tb4 = ((unsigned int)h * (MTOT * 16u) + ln) * 4u;
    const char* vbase = (const char*)valueT;
    float ax = 0.f, ay = 0.f;
#pragma unroll 4
    for (int p = 0; p < 16; ++p) {
        const int4  g  = s_g[sub][h][p];
        const f16x4 w4 = s_w[sub][h][p];
        const f16x2 v00 = *(const f16x2*)(vbase + (tb4 + ((unsigned int)g.x << 6)));
        const f16x2 v01 = *(const f16x2*)(vbase + (tb4 + ((unsigned int)g.y << 6)));
        const f16x2 v10 = *(const f16x2*)(vbase + (tb4 + ((unsigned int)g.z << 6)));
        const f16x2 v11 = *(const f16x2*)(vbase + (tb4 + ((unsigned int)g.w << 6)));
        const f16x2 wl = { w4.x, w4.y }, wh = { w4.z, w4.w };
        const f16x2 A1 = __builtin_shufflevector(v00, v01, 0, 2);  // (v00.x, v01.x)
        const f16x2 B1 = __builtin_shufflevector(v00, v01, 1, 3);  // (v00.y, v01.y)
        const f16x2 A2 = __builtin_shufflevector(v10, v11, 0, 2);
        const f16x2 B2 = __builtin_shufflevector(v10, v11, 1, 3);
        ax = __builtin_amdgcn_fdot2(A1, wl, ax, false);
        ax = __builtin_amdgcn_fdot2(A2, wh, ax, false);
        ay = __builtin_amdgcn_fdot2(B1, wl, ay, false);
        ay = __builtin_amdgcn_fdot2(B2, wh, ay, false);
    }
    f16x2 o = { (f16)ax, (f16)ay };
    *(f16x2*)&samp[(size_t)tok * 256 + h * 32 + ln * 2] = o;
}

// ---------------- LayerNorm: y = LN(xa + xb)*g + b ----------------
template<int MODE>
__global__ __launch_bounds__(256) void k_ln(
    const float* __restrict__ xa, const float* __restrict__ xb,
    const float* __restrict__ g, const float* __restrict__ be,
    float* __restrict__ yf, f16* __restrict__ yh, int M)
{
    const int row = blockIdx.x * 4 + (threadIdx.x >> 6);
    const int lane = threadIdx.x & 63;
    if (row >= M) return;
    const size_t o = (size_t)row * 256 + lane * 4;
    float4 a = *(const float4*)(xa + o);
    float4 b = *(const float4*)(xb + o);
    float x0 = a.x + b.x, x1 = a.y + b.y, x2 = a.z + b.z, x3 = a.w + b.w;
    float s  = x0 + x1 + x2 + x3;
    float ss = x0*x0 + x1*x1 + x2*x2 + x3*x3;
#pragma unroll
    for (int m = 1; m < 64; m <<= 1) {
        s  += __shfl_xor(s, m);
        ss += __shfl_xor(ss, m);
    }
    const float mean = s * (1.f / 256.f);
    const float var  = ss * (1.f / 256.f) - mean * mean;
    const float rstd = rsqrtf(var + 1e-5f);
    float4 gv = *(const float4*)(g + lane * 4);
    float4 bv = *(const float4*)(be + lane * 4);
    float y0 = (x0 - mean) * rstd * gv.x + bv.x;
    float y1 = (x1 - mean) * rstd * gv.y + bv.y;
    float y2 = (x2 - mean) * rstd * gv.z + bv.z;
    float y3 = (x3 - mean) * rstd * gv.w + bv.w;
    float4 yo = { y0, y1, y2, y3 };
    *(float4*)(yf + o) = yo;
    if (MODE == 0) {
        f16x4 hv = { (f16)y0, (f16)y1, (f16)y2, (f16)y3 };
        *(f16x4*)(yh + o) = hv;
    }
}

// ---------------- launch ----------------
extern "C" void kernel_launch(void* const* d_in, const int* in_sizes, int n_in,
                              void* d_out, int out_size, void* d_ws, size_t ws_size,
                              hipStream_t stream) {
    const float* src   = (const float*)d_in[0];
    const float* pos   = (const float*)d_in[1];
    const float* ref   = (const float*)d_in[2];
    const float* w_value = (const float*)d_in[5];
    const float* b_value = (const float*)d_in[6];
    const float* w_off   = (const float*)d_in[7];
    const float* b_off   = (const float*)d_in[8];
    const float* w_attn  = (const float*)d_in[9];
    const float* b_attn  = (const float*)d_in[10];
    const float* w_out   = (const float*)d_in[11];
    const float* b_out   = (const float*)d_in[12];
    const float* g1    = (const float*)d_in[13];
    const float* beta1 = (const float*)d_in[14];
    const float* w1    = (const float*)d_in[15];
    const float* b1    = (const float*)d_in[16];
    const float* w2    = (const float*)d_in[17];
    const float* b2    = (const float*)d_in[18];
    const float* g2    = (const float*)d_in[19];
    const float* beta2 = (const float*)d_in[20];

    char* ws = (char*)d_ws;
    f16*   wT      = (f16*)(ws + OFF_WT);
    f16*   oa      = (f16*)(ws + OFF_B4);     // fused off|attn f16 [M,384]
    float* y2buf   = (float*)(ws + OFF_B4);   // later: FFN2 out f32 [M,256]
    f16*   srch    = (f16*)(ws + OFF_B1);     // src f16
    f16*   samph   = (f16*)(ws + OFF_B1);     // later: sampled out f16
    f16*   qh      = (f16*)(ws + OFF_B2);     // query f16
    f16*   x1h     = (f16*)(ws + OFF_B2);     // later: LN1 out f16
    f16*   valueT  = (f16*)(ws + OFF_B3);     // value f16 head-blocked [8][M][32]
    f16*   hh      = (f16*)(ws + OFF_B3);     // later: FFN hidden f16 [M,1024]
    float* biasoa  = (float*)(ws + OFF_B5);   // concat bias f32 [384]
    float* src2    = (float*)(ws + OFF_B6);   // attn output f32
    float* x1f     = (float*)(ws + OFF_B7);   // LN1 out f32
    float* outp    = (float*)d_out;

    const int M = MTOT;
    const int MB = (M + 127) / 128;

    k_wconv<<<(WCONV_TOTAL + 255) / 256, 256, 0, stream>>>(
        w_value, w_off, w_attn, w_out, w1, w2, b_off, b_attn, wT, biasoa);
    k_prep<<<(M * 64 + 255) / 256, 256, 0, stream>>>(src, pos, srch, qh, M * 64);

    // value = src @ w_value + b_value -> head-blocked f16
    k_gemm128<false, 2><<<dim3(MB, 2), 256, 0, stream>>>(srch, wT + WT_V, b_value, valueT, M, 256, 256);
    // fused off|attn logits -> f16 [M,384]
    k_gemm128<false, 1><<<dim3(MB, 3), 256, 0, stream>>>(qh, wT + WT_OFF, biasoa, oa, M, 384, 256);
    // softmax + bilinear sampling (2 tokens per block)
    k_sample<<<dim3(MTOT / 2), 256, 0, stream>>>(oa, valueT, ref, samph);
    // out projection -> src2 f32
    k_gemm128<false, 0><<<dim3(MB, 2), 256, 0, stream>>>(samph, wT + WT_OUT, b_out, src2, M, 256, 256);
    // LN1
    k_ln<0><<<(M + 3) / 4, 256, 0, stream>>>(src, src2, g1, beta1, x1f, x1h, M);
    // FFN1: h = relu(x1 @ w1 + b1) f16
    k_gemm128<true, 1><<<dim3(MB, 8), 256, 0, stream>>>(x1h, wT + WT_W1, b1, hh, M, 1024, 256);
    // FFN2: y2 = h @ w2 + b2 f32
    k_gemm128<false, 0><<<dim3(MB, 2), 256, 0, stream>>>(hh, wT + WT_W2, b2, y2buf, M, 256, 1024);
    // LN2 -> d_out
    k_ln<1><<<(M + 3) / 4, 256, 0, stream>>>(x1f, y2buf, g2, beta2, outp, nullptr, M);

    (void)in_sizes; (void)n_in; (void)out_size; (void)ws_size;
}

// Round 4
// 309.826 us; speedup vs baseline: 2.1320x; 1.0749x over previous
//
#include <hip/hip_runtime.h>

// ---------------- problem constants ----------------
#define LQ   20197
#define MTOT 40394           // 2 * 20197

typedef _Float16 f16;
typedef _Float16 f16x8 __attribute__((ext_vector_type(8)));
typedef _Float16 f16x4 __attribute__((ext_vector_type(4)));
typedef _Float16 f16x2 __attribute__((ext_vector_type(2)));
typedef float    f32x4 __attribute__((ext_vector_type(4)));

// ---------------- workspace layout (bytes) ----------------
#define OFF_WT 0ull
#define OFF_B4 1507328ull      // oa f16 [M,384] -> later y2h f16 [M,256]
#define OFF_B1 42870784ull     // src f16 -> later samp f16
#define OFF_B2 63552512ull     // query f16 -> later x1h f16
#define OFF_B3 84234240ull     // valueT f16 [8][M][32]; later FFN hidden hh (B3..B7)
#define OFF_B5 104915968ull    // bias_oa f32 [384] (inside hh range; consumed before FFN1)
#define OFF_B6 125597696ull    // src2h f16 [M,256] (inside hh range; consumed before FFN1)

// wT element offsets (f16 elements)
#define WT_V    0
#define WT_OFF  65536          // off rows [256][256] then attn rows [128][256] contiguous
#define WT_ATTN 131072
#define WT_OUT  163840
#define WT_W1   229376
#define WT_W2   491520
#define WT_TOTAL 753664
#define WCONV_TOTAL (WT_TOTAL + 384)

// ---------------- async global->LDS, 16B per lane ----------------
__device__ __forceinline__ void gload_lds16(const f16* g, f16* l) {
    __builtin_amdgcn_global_load_lds(
        (const __attribute__((address_space(1))) unsigned int*)g,
        (__attribute__((address_space(3))) unsigned int*)l,
        16, 0, 0);
}

// ---------------- weight transpose+convert + bias concat ----------------
__global__ __launch_bounds__(256) void k_wconv(
    const float* __restrict__ wv, const float* __restrict__ woff,
    const float* __restrict__ wattn, const float* __restrict__ wout,
    const float* __restrict__ w1, const float* __restrict__ w2,
    const float* __restrict__ boff, const float* __restrict__ battn,
    f16* __restrict__ dst, float* __restrict__ biasoa)
{
    int gid = blockIdx.x * 256 + threadIdx.x;
    if (gid >= WCONV_TOTAL) return;
    if (gid >= WT_TOTAL) {
        int i = gid - WT_TOTAL;
        biasoa[i] = (i < 256) ? boff[i] : battn[i - 256];
        return;
    }
    const float* src; int Kd, Nd, base;
    if      (gid < 65536)  { src = wv;    Kd = 256;  Nd = 256;  base = 0; }
    else if (gid < 131072) { src = woff;  Kd = 256;  Nd = 256;  base = 65536; }
    else if (gid < 163840) { src = wattn; Kd = 256;  Nd = 128;  base = 131072; }
    else if (gid < 229376) { src = wout;  Kd = 256;  Nd = 256;  base = 163840; }
    else if (gid < 491520) { src = w1;    Kd = 256;  Nd = 1024; base = 229376; }
    else                   { src = w2;    Kd = 1024; Nd = 256;  base = 491520; }
    int loc = gid - base;
    int n = loc % Nd, k = loc / Nd;
    dst[base + n * Kd + k] = (f16)src[k * Nd + n];
}

// ---------------- prep: query = src + pos, cast both to f16 ----------------
__global__ __launch_bounds__(256) void k_prep(
    const float* __restrict__ src, const float* __restrict__ pos,
    f16* __restrict__ srch, f16* __restrict__ qh, int total4)
{
    int i = blockIdx.x * 256 + threadIdx.x;
    if (i >= total4) return;
    float4 s = ((const float4*)src)[i];
    float4 p = ((const float4*)pos)[i];
    f16x4 hs = { (f16)s.x, (f16)s.y, (f16)s.z, (f16)s.w };
    f16x4 hq = { (f16)(s.x + p.x), (f16)(s.y + p.y), (f16)(s.z + p.z), (f16)(s.w + p.w) };
    ((f16x4*)srch)[i] = hs;
    ((f16x4*)qh)[i]   = hq;
}

// ---------------- GEMM 128x128 tile, BK=32, double-buffered global_load_lds ----------------
// C[M,N] = A[M,K](f16) * Bt[N,K](f16)^T + bias
// OUTM: 0 = f32 row-major, 1 = f16 row-major, 2 = f16 head-blocked [N/32][M][32]
template<bool RELU, int OUTM>
__global__ __launch_bounds__(256) void k_gemm128(
    const f16* __restrict__ A, const f16* __restrict__ Bt,
    const float* __restrict__ bias, void* __restrict__ Cout,
    int M, int N, int K)
{
    __shared__ __align__(16) f16 As[2][128 * 32];
    __shared__ __align__(16) f16 Bs[2][128 * 32];
    const int t = threadIdx.x, wid = t >> 6, lane = t & 63;
    const int m0 = blockIdx.x * 128, n0 = blockIdx.y * 128;

    // staging: 8 chunks of 1KB per matrix per buffer; wave w does chunks w and w+4.
    const int c0 = wid, c1 = wid + 4;
    const int sr = lane >> 2, sk = (lane & 3) * 8;
    const int ra0 = min(m0 + c0 * 16 + sr, M - 1);
    const int ra1 = min(m0 + c1 * 16 + sr, M - 1);
    const f16* pa0 = A + (size_t)ra0 * K + sk;
    const f16* pa1 = A + (size_t)ra1 * K + sk;
    const f16* pb0 = Bt + (size_t)(n0 + c0 * 16 + sr) * K + sk;
    const f16* pb1 = Bt + (size_t)(n0 + c1 * 16 + sr) * K + sk;

    const int wr = wid >> 1, wc = wid & 1;
    const int fr = lane & 15, kb = (lane >> 4) * 8;

    f32x4 acc[4][4] = {};
    const int NT = K >> 5;

    // prologue: stage tile 0 into buffer 0
    gload_lds16(pa0, &As[0][c0 * 512]);
    gload_lds16(pa1, &As[0][c1 * 512]);
    gload_lds16(pb0, &Bs[0][c0 * 512]);
    gload_lds16(pb1, &Bs[0][c1 * 512]);
    __syncthreads();

    for (int tt = 0; tt < NT; ++tt) {
        const int cur = tt & 1, nxt = cur ^ 1;
        if (tt + 1 < NT) {                  // prefetch next tile; in flight during MFMA
            const int k0 = (tt + 1) << 5;
            gload_lds16(pa0 + k0, &As[nxt][c0 * 512]);
            gload_lds16(pa1 + k0, &As[nxt][c1 * 512]);
            gload_lds16(pb0 + k0, &Bs[nxt][c0 * 512]);
            gload_lds16(pb1 + k0, &Bs[nxt][c1 * 512]);
        }
        f16x8 af[4], bf[4];
#pragma unroll
        for (int i = 0; i < 4; ++i)
            af[i] = *(const f16x8*)&As[cur][(wr * 64 + i * 16 + fr) * 32 + kb];
#pragma unroll
        for (int i = 0; i < 4; ++i)
            bf[i] = *(const f16x8*)&Bs[cur][(wc * 64 + i * 16 + fr) * 32 + kb];
#pragma unroll
        for (int mi = 0; mi < 4; ++mi)
#pragma unroll
            for (int ni = 0; ni < 4; ++ni)
                acc[mi][ni] = __builtin_amdgcn_mfma_f32_16x16x32_f16(af[mi], bf[ni], acc[mi][ni], 0, 0, 0);
        __syncthreads();   // drains vmcnt(0)+lgkmcnt(0): next buffer ready, cur reads done
    }

    const int r4 = (lane >> 4) * 4;
#pragma unroll
    for (int ni = 0; ni < 4; ++ni) {
        const int col = n0 + wc * 64 + ni * 16 + fr;
        if (col >= N) continue;
        const float bv = bias[col];
#pragma unroll
        for (int mi = 0; mi < 4; ++mi) {
            const int rbase = m0 + wr * 64 + mi * 16 + r4;
#pragma unroll
            for (int j = 0; j < 4; ++j) {
                const int row = rbase + j;
                if (row < M) {
                    float v = acc[mi][ni][j] + bv;
                    if (RELU) v = fmaxf(v, 0.f);
                    if (OUTM == 0)      ((float*)Cout)[(size_t)row * N + col] = v;
                    else if (OUTM == 1) ((f16*)Cout)[(size_t)row * N + col] = (f16)v;
                    else ((f16*)Cout)[((size_t)(col >> 5) * M + row) * 32 + (col & 31)] = (f16)v;
                }
            }
        }
    }
}

// ---------------- fused softmax + deformable bilinear sampling ----------------
__global__ __launch_bounds__(256) void k_sample(
    const f16* __restrict__ oa, const f16* __restrict__ valueT,
    const float* __restrict__ ref, f16* __restrict__ samp)
{
    __shared__ int4  s_g[2][8][17];   // pad 17: avoid bank conflict across head groups
    __shared__ f16x4 s_w[2][8][17];
    const int t = threadIdx.x;
    const int sub = t >> 7;
    const int tok = blockIdx.x * 2 + sub;
    {
        const int h = (t >> 4) & 7, lp = t & 15, l = lp >> 2;
        const size_t row = (size_t)tok * 384;
        float logit = (float)oa[row + 256 + h * 16 + lp];
        float mx = logit;
#pragma unroll
        for (int m = 1; m < 16; m <<= 1) mx = fmaxf(mx, __shfl_xor(mx, m));
        float e = __expf(logit - mx);
        float sum = e;
#pragma unroll
        for (int m = 1; m < 16; m <<= 1) sum += __shfl_xor(sum, m);
        const float aw = e / sum;

        const float fW = (l == 0) ? 152.f : (l == 1) ? 76.f : (l == 2) ? 38.f : 19.f;
        const float fH = (l == 0) ? 100.f : (l == 1) ? 50.f : (l == 2) ? 25.f : 13.f;
        const int   W  = (l == 0) ? 152 : (l == 1) ? 76 : (l == 2) ? 38 : 19;
        const int   H  = (l == 0) ? 100 : (l == 1) ? 50 : (l == 2) ? 25 : 13;
        const int   st = (l == 0) ? 0 : (l == 1) ? 15200 : (l == 2) ? 19000 : 19950;

        const f16x2 ov = *(const f16x2*)&oa[row + h * 32 + lp * 2];
        const float rx = ref[(size_t)tok * 8 + l * 2 + 0];
        const float ry = ref[(size_t)tok * 8 + l * 2 + 1];
        const float x = rx * fW + (float)ov.x - 0.5f;
        const float y = ry * fH + (float)ov.y - 0.5f;
        const float xf = floorf(x), yf = floorf(y);
        const float fx = x - xf, fy = y - yf;
        const int x0 = (int)xf, y0 = (int)yf;

        const bool vx0 = (x0 >= 0) && (x0 < W);
        const bool vx1 = (x0 >= -1) && (x0 < W - 1);
        const bool vy0 = (y0 >= 0) && (y0 < H);
        const bool vy1 = (y0 >= -1) && (y0 < H - 1);
        const int x0c = min(max(x0, 0), W - 1), x1c = min(max(x0 + 1, 0), W - 1);
        const int y0c = min(max(y0, 0), H - 1), y1c = min(max(y0 + 1, 0), H - 1);

        const int n = (tok >= LQ) ? 1 : 0;
        const int i00 = n * LQ + st + y0c * W + x0c;
        const int dxs = x1c - x0c, dys = (y1c - y0c) * W;
        s_g[sub][h][lp] = make_int4(i00, i00 + dxs, i00 + dys, i00 + dys + dxs);

        const float w00 = (vx0 && vy0) ? (1.f - fx) * (1.f - fy) * aw : 0.f;
        const float w01 = (vx1 && vy0) ? fx * (1.f - fy) * aw : 0.f;
        const float w10 = (vx0 && vy1) ? (1.f - fx) * fy * aw : 0.f;
        const float w11 = (vx1 && vy1) ? fx * fy * aw : 0.f;
        f16x4 wv = { (f16)w00, (f16)w01, (f16)w10, (f16)w11 };
        s_w[sub][h][lp] = wv;
    }
    __syncthreads();

    const int h = (t >> 4) & 7, ln = t & 15;
    const unsigned int tb4 = ((unsigned int)h * (MTOT * 16u) + ln) * 4u;
    const char* vbase = (const char*)valueT;
    float ax = 0.f, ay = 0.f;
#pragma unroll 4
    for (int p = 0; p < 16; ++p) {
        const int4  g  = s_g[sub][h][p];
        const f16x4 w4 = s_w[sub][h][p];
        const f16x2 v00 = *(const f16x2*)(vbase + (tb4 + ((unsigned int)g.x << 6)));
        const f16x2 v01 = *(const f16x2*)(vbase + (tb4 + ((unsigned int)g.y << 6)));
        const f16x2 v10 = *(const f16x2*)(vbase + (tb4 + ((unsigned int)g.z << 6)));
        const f16x2 v11 = *(const f16x2*)(vbase + (tb4 + ((unsigned int)g.w << 6)));
        const f16x2 wl = { w4.x, w4.y }, wh = { w4.z, w4.w };
        const f16x2 A1 = __builtin_shufflevector(v00, v01, 0, 2);
        const f16x2 B1 = __builtin_shufflevector(v00, v01, 1, 3);
        const f16x2 A2 = __builtin_shufflevector(v10, v11, 0, 2);
        const f16x2 B2 = __builtin_shufflevector(v10, v11, 1, 3);
        ax = __builtin_amdgcn_fdot2(A1, wl, ax, false);
        ax = __builtin_amdgcn_fdot2(A2, wh, ax, false);
        ay = __builtin_amdgcn_fdot2(B1, wl, ay, false);
        ay = __builtin_amdgcn_fdot2(B2, wh, ay, false);
    }
    f16x2 o = { (f16)ax, (f16)ay };
    *(f16x2*)&samp[(size_t)tok * 256 + h * 32 + ln * 2] = o;
}

// ---------------- LN1: x1h = (f16) LN(src_f32 + src2_f16) ----------------
__global__ __launch_bounds__(256) void k_ln1(
    const float* __restrict__ xa, const f16* __restrict__ xb,
    const float* __restrict__ g, const float* __restrict__ be,
    f16* __restrict__ yh, int M)
{
    const int row = blockIdx.x * 4 + (threadIdx.x >> 6);
    const int lane = threadIdx.x & 63;
    if (row >= M) return;
    const size_t o = (size_t)row * 256 + lane * 4;
    float4 a = *(const float4*)(xa + o);
    f16x4  b = *(const f16x4*)(xb + o);
    float x0 = a.x + (float)b.x, x1 = a.y + (float)b.y;
    float x2 = a.z + (float)b.z, x3 = a.w + (float)b.w;
    float s  = x0 + x1 + x2 + x3;
    float ss = x0*x0 + x1*x1 + x2*x2 + x3*x3;
#pragma unroll
    for (int m = 1; m < 64; m <<= 1) { s += __shfl_xor(s, m); ss += __shfl_xor(ss, m); }
    const float mean = s * (1.f / 256.f);
    const float var  = ss * (1.f / 256.f) - mean * mean;
    const float rstd = rsqrtf(var + 1e-5f);
    float4 gv = *(const float4*)(g + lane * 4);
    float4 bv = *(const float4*)(be + lane * 4);
    f16x4 hv = { (f16)((x0 - mean) * rstd * gv.x + bv.x),
                 (f16)((x1 - mean) * rstd * gv.y + bv.y),
                 (f16)((x2 - mean) * rstd * gv.z + bv.z),
                 (f16)((x3 - mean) * rstd * gv.w + bv.w) };
    *(f16x4*)(yh + o) = hv;
}

// ---------------- LN2: out_f32 = LN(x1_f16 + y2_f16) ----------------
__global__ __launch_bounds__(256) void k_ln2(
    const f16* __restrict__ xa, const f16* __restrict__ xb,
    const float* __restrict__ g, const float* __restrict__ be,
    float* __restrict__ yf, int M)
{
    const int row = blockIdx.x * 4 + (threadIdx.x >> 6);
    const int lane = threadIdx.x & 63;
    if (row >= M) return;
    const size_t o = (size_t)row * 256 + lane * 4;
    f16x4 a = *(const f16x4*)(xa + o);
    f16x4 b = *(const f16x4*)(xb + o);
    float x0 = (float)a.x + (float)b.x, x1 = (float)a.y + (float)b.y;
    float x2 = (float)a.z + (float)b.z, x3 = (float)a.w + (float)b.w;
    float s  = x0 + x1 + x2 + x3;
    float ss = x0*x0 + x1*x1 + x2*x2 + x3*x3;
#pragma unroll
    for (int m = 1; m < 64; m <<= 1) { s += __shfl_xor(s, m); ss += __shfl_xor(ss, m); }
    const float mean = s * (1.f / 256.f);
    const float var  = ss * (1.f / 256.f) - mean * mean;
    const float rstd = rsqrtf(var + 1e-5f);
    float4 gv = *(const float4*)(g + lane * 4);
    float4 bv = *(const float4*)(be + lane * 4);
    float4 yo = { (x0 - mean) * rstd * gv.x + bv.x,
                  (x1 - mean) * rstd * gv.y + bv.y,
                  (x2 - mean) * rstd * gv.z + bv.z,
                  (x3 - mean) * rstd * gv.w + bv.w };
    *(float4*)(yf + o) = yo;
}

// ---------------- launch ----------------
extern "C" void kernel_launch(void* const* d_in, const int* in_sizes, int n_in,
                              void* d_out, int out_size, void* d_ws, size_t ws_size,
                              hipStream_t stream) {
    const float* src   = (const float*)d_in[0];
    const float* pos   = (const float*)d_in[1];
    const float* ref   = (const float*)d_in[2];
    const float* w_value = (const float*)d_in[5];
    const float* b_value = (const float*)d_in[6];
    const float* w_off   = (const float*)d_in[7];
    const float* b_off   = (const float*)d_in[8];
    const float* w_attn  = (const float*)d_in[9];
    const float* b_attn  = (const float*)d_in[10];
    const float* w_out   = (const float*)d_in[11];
    const float* b_out   = (const float*)d_in[12];
    const float* g1    = (const float*)d_in[13];
    const float* beta1 = (const float*)d_in[14];
    const float* w1    = (const float*)d_in[15];
    const float* b1    = (const float*)d_in[16];
    const float* w2    = (const float*)d_in[17];
    const float* b2    = (const float*)d_in[18];
    const float* g2    = (const float*)d_in[19];
    const float* beta2 = (const float*)d_in[20];

    char* ws = (char*)d_ws;
    f16*   wT      = (f16*)(ws + OFF_WT);
    f16*   oa      = (f16*)(ws + OFF_B4);     // fused off|attn f16 [M,384]
    f16*   y2h     = (f16*)(ws + OFF_B4);     // later: FFN2 out f16 [M,256]
    f16*   srch    = (f16*)(ws + OFF_B1);     // src f16
    f16*   samph   = (f16*)(ws + OFF_B1);     // later: sampled out f16
    f16*   qh      = (f16*)(ws + OFF_B2);     // query f16
    f16*   x1h     = (f16*)(ws + OFF_B2);     // later: LN1 out f16
    f16*   valueT  = (f16*)(ws + OFF_B3);     // value f16 head-blocked [8][M][32]
    f16*   hh      = (f16*)(ws + OFF_B3);     // later: FFN hidden f16 [M,1024]
    float* biasoa  = (float*)(ws + OFF_B5);   // concat bias f32 [384]
    f16*   src2h   = (f16*)(ws + OFF_B6);     // attn output f16 [M,256]
    float* outp    = (float*)d_out;

    const int M = MTOT;
    const int MB = (M + 127) / 128;

    k_wconv<<<(WCONV_TOTAL + 255) / 256, 256, 0, stream>>>(
        w_value, w_off, w_attn, w_out, w1, w2, b_off, b_attn, wT, biasoa);
    k_prep<<<(M * 64 + 255) / 256, 256, 0, stream>>>(src, pos, srch, qh, M * 64);

    // value = src @ w_value + b_value -> head-blocked f16
    k_gemm128<false, 2><<<dim3(MB, 2), 256, 0, stream>>>(srch, wT + WT_V, b_value, valueT, M, 256, 256);
    // fused off|attn logits -> f16 [M,384]
    k_gemm128<false, 1><<<dim3(MB, 3), 256, 0, stream>>>(qh, wT + WT_OFF, biasoa, oa, M, 384, 256);
    // softmax + bilinear sampling
    k_sample<<<dim3(MTOT / 2), 256, 0, stream>>>(oa, valueT, ref, samph);
    // out projection -> src2 f16
    k_gemm128<false, 1><<<dim3(MB, 2), 256, 0, stream>>>(samph, wT + WT_OUT, b_out, src2h, M, 256, 256);
    // LN1 -> x1h f16
    k_ln1<<<(M + 3) / 4, 256, 0, stream>>>(src, src2h, g1, beta1, x1h, M);
    // FFN1: h = relu(x1 @ w1 + b1) f16
    k_gemm128<true, 1><<<dim3(MB, 8), 256, 0, stream>>>(x1h, wT + WT_W1, b1, hh, M, 1024, 256);
    // FFN2: y2 = h @ w2 + b2 -> f16
    k_gemm128<false, 1><<<dim3(MB, 2), 256, 0, stream>>>(hh, wT + WT_W2, b2, y2h, M, 256, 1024);
    // LN2 -> d_out f32
    k_ln2<<<(M + 3) / 4, 256, 0, stream>>>(x1h, y2h, g2, beta2, outp, M);

    (void)in_sizes; (void)n_in; (void)out_size; (void)ws_size;
}

// Round 5
// 221.208 us; speedup vs baseline: 2.9861x; 1.4006x over previous
//
#include <hip/hip_runtime.h>

// ---------------- problem constants ----------------
#define LQ   20197
#define MTOT 40394           // 2 * 20197

typedef _Float16 f16;
typedef _Float16 f16x8 __attribute__((ext_vector_type(8)));
typedef _Float16 f16x4 __attribute__((ext_vector_type(4)));
typedef _Float16 f16x2 __attribute__((ext_vector_type(2)));
typedef float    f32x4 __attribute__((ext_vector_type(4)));

// ---------------- workspace layout (bytes) ----------------
#define OFF_WT 0ull
#define OFF_B4 1507328ull      // oa f16 [M,384] -> later y2h f16 [M,256]
#define OFF_B1 42870784ull     // src f16 -> later samp f16
#define OFF_B2 63552512ull     // query f16 -> later x1h f16
#define OFF_B3 84234240ull     // valueT f16 [8][M][32]; later FFN hidden hh (B3..B7)
#define OFF_B5 104915968ull    // bias_oa f32 [384] (inside hh range; consumed before FFN1)
#define OFF_B6 125597696ull    // src2h f16 [M,256] (inside hh range; consumed before FFN1)

// wT element offsets (f16 elements)
#define WT_V    0
#define WT_OFF  65536          // off rows [256][256] then attn rows [128][256] contiguous
#define WT_ATTN 131072
#define WT_OUT  163840
#define WT_W1   229376
#define WT_W2   491520
#define WT_TOTAL 753664
#define WCONV_TOTAL (WT_TOTAL + 384)

// ---------------- async global->LDS, 16B per lane ----------------
__device__ __forceinline__ void gload_lds16(const f16* g, f16* l) {
    __builtin_amdgcn_global_load_lds(
        (const __attribute__((address_space(1))) unsigned int*)g,
        (__attribute__((address_space(3))) unsigned int*)l,
        16, 0, 0);
}

// ---------------- weight transpose+convert + bias concat ----------------
__global__ __launch_bounds__(256) void k_wconv(
    const float* __restrict__ wv, const float* __restrict__ woff,
    const float* __restrict__ wattn, const float* __restrict__ wout,
    const float* __restrict__ w1, const float* __restrict__ w2,
    const float* __restrict__ boff, const float* __restrict__ battn,
    f16* __restrict__ dst, float* __restrict__ biasoa)
{
    int gid = blockIdx.x * 256 + threadIdx.x;
    if (gid >= WCONV_TOTAL) return;
    if (gid >= WT_TOTAL) {
        int i = gid - WT_TOTAL;
        biasoa[i] = (i < 256) ? boff[i] : battn[i - 256];
        return;
    }
    const float* src; int Kd, Nd, base;
    if      (gid < 65536)  { src = wv;    Kd = 256;  Nd = 256;  base = 0; }
    else if (gid < 131072) { src = woff;  Kd = 256;  Nd = 256;  base = 65536; }
    else if (gid < 163840) { src = wattn; Kd = 256;  Nd = 128;  base = 131072; }
    else if (gid < 229376) { src = wout;  Kd = 256;  Nd = 256;  base = 163840; }
    else if (gid < 491520) { src = w1;    Kd = 256;  Nd = 1024; base = 229376; }
    else                   { src = w2;    Kd = 1024; Nd = 256;  base = 491520; }
    int loc = gid - base;
    int n = loc % Nd, k = loc / Nd;
    dst[base + n * Kd + k] = (f16)src[k * Nd + n];
}

// ---------------- prep: query = src + pos, cast both to f16 ----------------
__global__ __launch_bounds__(256) void k_prep(
    const float* __restrict__ src, const float* __restrict__ pos,
    f16* __restrict__ srch, f16* __restrict__ qh, int total4)
{
    int i = blockIdx.x * 256 + threadIdx.x;
    if (i >= total4) return;
    float4 s = ((const float4*)src)[i];
    float4 p = ((const float4*)pos)[i];
    f16x4 hs = { (f16)s.x, (f16)s.y, (f16)s.z, (f16)s.w };
    f16x4 hq = { (f16)(s.x + p.x), (f16)(s.y + p.y), (f16)(s.z + p.z), (f16)(s.w + p.w) };
    ((f16x4*)srch)[i] = hs;
    ((f16x4*)qh)[i]   = hq;
}

// ---------------- GEMM 128x128 tile, BK=32, dbuf global_load_lds, XCD swizzle ----------------
// C[M,N] = A[M,K](f16) * Bt[N,K](f16)^T + bias ; N % 128 == 0 assumed.
// 1D grid padded to multiple of 8; bijective XCD swizzle, N-tile fastest per XCD
// (A-panel fetched once per XCD, L2-hit for remaining N-tiles).
// Epilogue stages C tile in LDS (stride 136 f16, 2-way conflicts only = free),
// then writes fully-coalesced segments.
// OUTM: 1 = f16 row-major [M][N], 2 = f16 head-blocked [N/32][M][32]
template<bool RELU, int OUTM>
__global__ __launch_bounds__(256) void k_gemm128(
    const f16* __restrict__ A, const f16* __restrict__ Bt,
    const float* __restrict__ bias, void* __restrict__ Cout,
    int M, int N, int K)
{
    __shared__ __align__(16) char pool[34816];   // staging 32KB  |  C-tile 128*136*2B
    f16* const sm = (f16*)pool;

    const int NBn = N >> 7;
    const int MBn = (M + 127) >> 7;
    const int tiles = MBn * NBn;
    const int q = gridDim.x >> 3;                 // grid padded to %8
    const int bid = blockIdx.x;
    const int swz = (bid & 7) * q + (bid >> 3);   // bijective XCD swizzle
    if (swz >= tiles) return;
    const int m0 = (swz / NBn) << 7;
    const int n0 = (swz % NBn) << 7;

    const int t = threadIdx.x, wid = t >> 6, lane = t & 63;

    // staging: 8 chunks of 1KB per matrix per buffer; wave w does chunks w and w+4.
    const int c0 = wid, c1 = wid + 4;
    const int sr = lane >> 2, sk = (lane & 3) * 8;
    const int ra0 = min(m0 + c0 * 16 + sr, M - 1);
    const int ra1 = min(m0 + c1 * 16 + sr, M - 1);
    const f16* pa0 = A + (size_t)ra0 * K + sk;
    const f16* pa1 = A + (size_t)ra1 * K + sk;
    const f16* pb0 = Bt + (size_t)(n0 + c0 * 16 + sr) * K + sk;
    const f16* pb1 = Bt + (size_t)(n0 + c1 * 16 + sr) * K + sk;
    // LDS f16-unit offsets: buf b: A at b*8192, B at b*8192+4096
    const int lo0 = c0 * 512, lo1 = c1 * 512;

    const int wr = wid >> 1, wc = wid & 1;
    const int fr = lane & 15, kb = (lane >> 4) * 8;

    f32x4 acc[4][4] = {};
    const int NT = K >> 5;

    // prologue: stage tile 0 into buffer 0
    gload_lds16(pa0, sm + lo0);
    gload_lds16(pa1, sm + lo1);
    gload_lds16(pb0, sm + 4096 + lo0);
    gload_lds16(pb1, sm + 4096 + lo1);
    __syncthreads();

    for (int tt = 0; tt < NT; ++tt) {
        const int cur = (tt & 1) << 13, nxt = cur ^ 8192;
        if (tt + 1 < NT) {                  // prefetch next tile (in flight during MFMA)
            const int k0 = (tt + 1) << 5;
            gload_lds16(pa0 + k0, sm + nxt + lo0);
            gload_lds16(pa1 + k0, sm + nxt + lo1);
            gload_lds16(pb0 + k0, sm + nxt + 4096 + lo0);
            gload_lds16(pb1 + k0, sm + nxt + 4096 + lo1);
        }
        f16x8 af[4], bf[4];
#pragma unroll
        for (int i = 0; i < 4; ++i)
            af[i] = *(const f16x8*)&sm[cur + (wr * 64 + i * 16 + fr) * 32 + kb];
#pragma unroll
        for (int i = 0; i < 4; ++i)
            bf[i] = *(const f16x8*)&sm[cur + 4096 + (wc * 64 + i * 16 + fr) * 32 + kb];
#pragma unroll
        for (int mi = 0; mi < 4; ++mi)
#pragma unroll
            for (int ni = 0; ni < 4; ++ni)
                acc[mi][ni] = __builtin_amdgcn_mfma_f32_16x16x32_f16(af[mi], bf[ni], acc[mi][ni], 0, 0, 0);
        __syncthreads();
    }

    // ---- epilogue: acc -> LDS (stride 136) -> coalesced global ----
    const int r4 = (lane >> 4) * 4;
#pragma unroll
    for (int ni = 0; ni < 4; ++ni) {
        const int lcol = wc * 64 + ni * 16 + fr;
        const float bv = bias[n0 + lcol];
#pragma unroll
        for (int mi = 0; mi < 4; ++mi) {
#pragma unroll
            for (int j = 0; j < 4; ++j) {
                float v = acc[mi][ni][j] + bv;
                if (RELU) v = fmaxf(v, 0.f);
                sm[(wr * 64 + mi * 16 + r4 + j) * 136 + lcol] = (f16)v;
            }
        }
    }
    __syncthreads();

    if (OUTM == 1) {
        const int rr = t >> 4, cc = (t & 15) * 8;   // 16 rows/pass, 16B per thread
#pragma unroll
        for (int pass = 0; pass < 8; ++pass) {
            const int r = pass * 16 + rr;
            const int row = m0 + r;
            if (row < M) {
                f16x8 v = *(const f16x8*)&sm[r * 136 + cc];
                *(f16x8*)&((f16*)Cout)[(size_t)row * N + n0 + cc] = v;
            }
        }
    } else {
        // head-blocked: [(col>>5)][row][col&31]; per cb, rows are contiguous 64B
        const int cbl = t >> 6, rr = (t & 63) >> 2, cc = (t & 3) * 8;
        const size_t cb = (size_t)((n0 >> 5) + cbl);
#pragma unroll
        for (int pass = 0; pass < 8; ++pass) {
            const int r = pass * 16 + rr;
            const int row = m0 + r;
            if (row < M) {
                f16x8 v = *(const f16x8*)&sm[r * 136 + cbl * 32 + cc];
                *(f16x8*)&((f16*)Cout)[(cb * M + row) * 32 + cc] = v;
            }
        }
    }
}

// ---------------- fused softmax + deformable bilinear sampling ----------------
__global__ __launch_bounds__(256) void k_sample(
    const f16* __restrict__ oa, const f16* __restrict__ valueT,
    const float* __restrict__ ref, f16* __restrict__ samp)
{
    __shared__ int4  s_g[2][8][17];   // pad 17: avoid bank conflict across head groups
    __shared__ f16x4 s_w[2][8][17];
    const int t = threadIdx.x;
    const int sub = t >> 7;
    const int tok = blockIdx.x * 2 + sub;
    {
        const int h = (t >> 4) & 7, lp = t & 15, l = lp >> 2;
        const size_t row = (size_t)tok * 384;
        float logit = (float)oa[row + 256 + h * 16 + lp];
        float mx = logit;
#pragma unroll
        for (int m = 1; m < 16; m <<= 1) mx = fmaxf(mx, __shfl_xor(mx, m));
        float e = __expf(logit - mx);
        float sum = e;
#pragma unroll
        for (int m = 1; m < 16; m <<= 1) sum += __shfl_xor(sum, m);
        const float aw = e / sum;

        const float fW = (l == 0) ? 152.f : (l == 1) ? 76.f : (l == 2) ? 38.f : 19.f;
        const float fH = (l == 0) ? 100.f : (l == 1) ? 50.f : (l == 2) ? 25.f : 13.f;
        const int   W  = (l == 0) ? 152 : (l == 1) ? 76 : (l == 2) ? 38 : 19;
        const int   H  = (l == 0) ? 100 : (l == 1) ? 50 : (l == 2) ? 25 : 13;
        const int   st = (l == 0) ? 0 : (l == 1) ? 15200 : (l == 2) ? 19000 : 19950;

        const f16x2 ov = *(const f16x2*)&oa[row + h * 32 + lp * 2];
        const float rx = ref[(size_t)tok * 8 + l * 2 + 0];
        const float ry = ref[(size_t)tok * 8 + l * 2 + 1];
        const float x = rx * fW + (float)ov.x - 0.5f;
        const float y = ry * fH + (float)ov.y - 0.5f;
        const float xf = floorf(x), yf = floorf(y);
        const float fx = x - xf, fy = y - yf;
        const int x0 = (int)xf, y0 = (int)yf;

        const bool vx0 = (x0 >= 0) && (x0 < W);
        const bool vx1 = (x0 >= -1) && (x0 < W - 1);
        const bool vy0 = (y0 >= 0) && (y0 < H);
        const bool vy1 = (y0 >= -1) && (y0 < H - 1);
        const int x0c = min(max(x0, 0), W - 1), x1c = min(max(x0 + 1, 0), W - 1);
        const int y0c = min(max(y0, 0), H - 1), y1c = min(max(y0 + 1, 0), H - 1);

        const int n = (tok >= LQ) ? 1 : 0;
        const int i00 = n * LQ + st + y0c * W + x0c;
        const int dxs = x1c - x0c, dys = (y1c - y0c) * W;
        s_g[sub][h][lp] = make_int4(i00, i00 + dxs, i00 + dys, i00 + dys + dxs);

        const float w00 = (vx0 && vy0) ? (1.f - fx) * (1.f - fy) * aw : 0.f;
        const float w01 = (vx1 && vy0) ? fx * (1.f - fy) * aw : 0.f;
        const float w10 = (vx0 && vy1) ? (1.f - fx) * fy * aw : 0.f;
        const float w11 = (vx1 && vy1) ? fx * fy * aw : 0.f;
        f16x4 wv = { (f16)w00, (f16)w01, (f16)w10, (f16)w11 };
        s_w[sub][h][lp] = wv;
    }
    __syncthreads();

    const int h = (t >> 4) & 7, ln = t & 15;
    const unsigned int tb4 = ((unsigned int)h * (MTOT * 16u) + ln) * 4u;
    const char* vbase = (const char*)valueT;
    float ax = 0.f, ay = 0.f;
#pragma unroll 4
    for (int p = 0; p < 16; ++p) {
        const int4  g  = s_g[sub][h][p];
        const f16x4 w4 = s_w[sub][h][p];
        const f16x2 v00 = *(const f16x2*)(vbase + (tb4 + ((unsigned int)g.x << 6)));
        const f16x2 v01 = *(const f16x2*)(vbase + (tb4 + ((unsigned int)g.y << 6)));
        const f16x2 v10 = *(const f16x2*)(vbase + (tb4 + ((unsigned int)g.z << 6)));
        const f16x2 v11 = *(const f16x2*)(vbase + (tb4 + ((unsigned int)g.w << 6)));
        const f16x2 wl = { w4.x, w4.y }, wh = { w4.z, w4.w };
        const f16x2 A1 = __builtin_shufflevector(v00, v01, 0, 2);
        const f16x2 B1 = __builtin_shufflevector(v00, v01, 1, 3);
        const f16x2 A2 = __builtin_shufflevector(v10, v11, 0, 2);
        const f16x2 B2 = __builtin_shufflevector(v10, v11, 1, 3);
        ax = __builtin_amdgcn_fdot2(A1, wl, ax, false);
        ax = __builtin_amdgcn_fdot2(A2, wh, ax, false);
        ay = __builtin_amdgcn_fdot2(B1, wl, ay, false);
        ay = __builtin_amdgcn_fdot2(B2, wh, ay, false);
    }
    f16x2 o = { (f16)ax, (f16)ay };
    *(f16x2*)&samp[(size_t)tok * 256 + h * 32 + ln * 2] = o;
}

// ---------------- LN1: x1h = (f16) LN(src_f32 + src2_f16) ----------------
__global__ __launch_bounds__(256) void k_ln1(
    const float* __restrict__ xa, const f16* __restrict__ xb,
    const float* __restrict__ g, const float* __restrict__ be,
    f16* __restrict__ yh, int M)
{
    const int row = blockIdx.x * 4 + (threadIdx.x >> 6);
    const int lane = threadIdx.x & 63;
    if (row >= M) return;
    const size_t o = (size_t)row * 256 + lane * 4;
    float4 a = *(const float4*)(xa + o);
    f16x4  b = *(const f16x4*)(xb + o);
    float x0 = a.x + (float)b.x, x1 = a.y + (float)b.y;
    float x2 = a.z + (float)b.z, x3 = a.w + (float)b.w;
    float s  = x0 + x1 + x2 + x3;
    float ss = x0*x0 + x1*x1 + x2*x2 + x3*x3;
#pragma unroll
    for (int m = 1; m < 64; m <<= 1) { s += __shfl_xor(s, m); ss += __shfl_xor(ss, m); }
    const float mean = s * (1.f / 256.f);
    const float var  = ss * (1.f / 256.f) - mean * mean;
    const float rstd = rsqrtf(var + 1e-5f);
    float4 gv = *(const float4*)(g + lane * 4);
    float4 bv = *(const float4*)(be + lane * 4);
    f16x4 hv = { (f16)((x0 - mean) * rstd * gv.x + bv.x),
                 (f16)((x1 - mean) * rstd * gv.y + bv.y),
                 (f16)((x2 - mean) * rstd * gv.z + bv.z),
                 (f16)((x3 - mean) * rstd * gv.w + bv.w) };
    *(f16x4*)(yh + o) = hv;
}

// ---------------- LN2: out_f32 = LN(x1_f16 + y2_f16) ----------------
__global__ __launch_bounds__(256) void k_ln2(
    const f16* __restrict__ xa, const f16* __restrict__ xb,
    const float* __restrict__ g, const float* __restrict__ be,
    float* __restrict__ yf, int M)
{
    const int row = blockIdx.x * 4 + (threadIdx.x >> 6);
    const int lane = threadIdx.x & 63;
    if (row >= M) return;
    const size_t o = (size_t)row * 256 + lane * 4;
    f16x4 a = *(const f16x4*)(xa + o);
    f16x4 b = *(const f16x4*)(xb + o);
    float x0 = (float)a.x + (float)b.x, x1 = (float)a.y + (float)b.y;
    float x2 = (float)a.z + (float)b.z, x3 = (float)a.w + (float)b.w;
    float s  = x0 + x1 + x2 + x3;
    float ss = x0*x0 + x1*x1 + x2*x2 + x3*x3;
#pragma unroll
    for (int m = 1; m < 64; m <<= 1) { s += __shfl_xor(s, m); ss += __shfl_xor(ss, m); }
    const float mean = s * (1.f / 256.f);
    const float var  = ss * (1.f / 256.f) - mean * mean;
    const float rstd = rsqrtf(var + 1e-5f);
    float4 gv = *(const float4*)(g + lane * 4);
    float4 bv = *(const float4*)(be + lane * 4);
    float4 yo = { (x0 - mean) * rstd * gv.x + bv.x,
                  (x1 - mean) * rstd * gv.y + bv.y,
                  (x2 - mean) * rstd * gv.z + bv.z,
                  (x3 - mean) * rstd * gv.w + bv.w };
    *(float4*)(yf + o) = yo;
}

// ---------------- launch ----------------
extern "C" void kernel_launch(void* const* d_in, const int* in_sizes, int n_in,
                              void* d_out, int out_size, void* d_ws, size_t ws_size,
                              hipStream_t stream) {
    const float* src   = (const float*)d_in[0];
    const float* pos   = (const float*)d_in[1];
    const float* ref   = (const float*)d_in[2];
    const float* w_value = (const float*)d_in[5];
    const float* b_value = (const float*)d_in[6];
    const float* w_off   = (const float*)d_in[7];
    const float* b_off   = (const float*)d_in[8];
    const float* w_attn  = (const float*)d_in[9];
    const float* b_attn  = (const float*)d_in[10];
    const float* w_out   = (const float*)d_in[11];
    const float* b_out   = (const float*)d_in[12];
    const float* g1    = (const float*)d_in[13];
    const float* beta1 = (const float*)d_in[14];
    const float* w1    = (const float*)d_in[15];
    const float* b1    = (const float*)d_in[16];
    const float* w2    = (const float*)d_in[17];
    const float* b2    = (const float*)d_in[18];
    const float* g2    = (const float*)d_in[19];
    const float* beta2 = (const float*)d_in[20];

    char* ws = (char*)d_ws;
    f16*   wT      = (f16*)(ws + OFF_WT);
    f16*   oa      = (f16*)(ws + OFF_B4);     // fused off|attn f16 [M,384]
    f16*   y2h     = (f16*)(ws + OFF_B4);     // later: FFN2 out f16 [M,256]
    f16*   srch    = (f16*)(ws + OFF_B1);     // src f16
    f16*   samph   = (f16*)(ws + OFF_B1);     // later: sampled out f16
    f16*   qh      = (f16*)(ws + OFF_B2);     // query f16
    f16*   x1h     = (f16*)(ws + OFF_B2);     // later: LN1 out f16
    f16*   valueT  = (f16*)(ws + OFF_B3);     // value f16 head-blocked [8][M][32]
    f16*   hh      = (f16*)(ws + OFF_B3);     // later: FFN hidden f16 [M,1024]
    float* biasoa  = (float*)(ws + OFF_B5);   // concat bias f32 [384]
    f16*   src2h   = (f16*)(ws + OFF_B6);     // attn output f16 [M,256]
    float* outp    = (float*)d_out;

    const int M = MTOT;
    const int MB = (M + 127) / 128;
    auto grid8 = [&](int nb) { return ((MB * nb) + 7) & ~7; };   // pad to %8 for swizzle

    k_wconv<<<(WCONV_TOTAL + 255) / 256, 256, 0, stream>>>(
        w_value, w_off, w_attn, w_out, w1, w2, b_off, b_attn, wT, biasoa);
    k_prep<<<(M * 64 + 255) / 256, 256, 0, stream>>>(src, pos, srch, qh, M * 64);

    // value = src @ w_value + b_value -> head-blocked f16
    k_gemm128<false, 2><<<grid8(2), 256, 0, stream>>>(srch, wT + WT_V, b_value, valueT, M, 256, 256);
    // fused off|attn logits -> f16 [M,384]
    k_gemm128<false, 1><<<grid8(3), 256, 0, stream>>>(qh, wT + WT_OFF, biasoa, oa, M, 384, 256);
    // softmax + bilinear sampling
    k_sample<<<dim3(MTOT / 2), 256, 0, stream>>>(oa, valueT, ref, samph);
    // out projection -> src2 f16
    k_gemm128<false, 1><<<grid8(2), 256, 0, stream>>>(samph, wT + WT_OUT, b_out, src2h, M, 256, 256);
    // LN1 -> x1h f16
    k_ln1<<<(M + 3) / 4, 256, 0, stream>>>(src, src2h, g1, beta1, x1h, M);
    // FFN1: h = relu(x1 @ w1 + b1) f16
    k_gemm128<true, 1><<<grid8(8), 256, 0, stream>>>(x1h, wT + WT_W1, b1, hh, M, 1024, 256);
    // FFN2: y2 = h @ w2 + b2 -> f16
    k_gemm128<false, 1><<<grid8(2), 256, 0, stream>>>(hh, wT + WT_W2, b2, y2h, M, 256, 1024);
    // LN2 -> d_out f32
    k_ln2<<<(M + 3) / 4, 256, 0, stream>>>(x1h, y2h, g2, beta2, outp, M);

    (void)in_sizes; (void)n_in; (void)out_size; (void)ws_size;
}